// Round 4
// baseline (633.466 us; speedup 1.0000x reference)
//
#include <hip/hip_runtime.h>
#include <math.h>

#define Hd 1024
#define Td 64
#define Vd 32000

// ---- static workspace float offsets ----
static const size_t OFF_ENCX  = 0;         // 64*1024
static const size_t OFF_DECX  = 65536;     // 64*1024
static const size_t OFF_GENC  = 131072;    // 64*4096
static const size_t OFF_GDEC  = 393216;    // 64*4096
static const size_t OFF_BSE   = 655360;    // 4096
static const size_t OFF_BSD   = 659456;    // 4096
static const size_t OFF_TEN   = 663552;    // 32
static const size_t OFF_HALL  = 663584;    // 64*1024 (ends 729120)
static const size_t OFF_REP   = 729600;    // replicated mailboxes

// Each replica: 130 step-buffers x 1024 float2 (flagged h) + 512 float2 (mean/logvar)
#define HB_ULL   133120u          // 130*1024 ULL entries
#define REP_ULL  133632u          // + 512 mf entries
#define FLAGB    0x3f800000u

__device__ __forceinline__ float fsigm(float x) {
  return __fdividef(1.f, 1.f + __expf(-x));
}
__device__ __forceinline__ float ftanh(float x) {
  return 1.f - __fdividef(2.f, __expf(2.f * x) + 1.f);
}

// producer: store flagged value to all R replicas
__device__ __forceinline__ void st_rep(unsigned long long* base, size_t idx, float v, int R) {
  unsigned long long u = 0x3f80000000000000ull | (unsigned long long)__float_as_uint(v);
  unsigned long long* p = base + idx;
  for (int r = 0; r < R; ++r) {
    __hip_atomic_store(p, u, __ATOMIC_RELAXED, __HIP_MEMORY_SCOPE_AGENT);
    p += REP_ULL;
  }
}

// wave-0 poll of 1024 flagged entries; lane l owns entries l+64k, k=0..15.
// Writes values to dst[0..1023] in LDS (conflict-free b32 pattern).
__device__ __forceinline__ void poll1024(const unsigned long long* ent, float* dst, int lane) {
  const unsigned long long* p0 = ent + lane;
  const unsigned long long* p1 = p0 + 512;
  float2 a0,a1,a2,a3,a4,a5,a6,a7,a8,a9,aa,ab,ac,ad,ae,af;
  for (;;) {
    asm volatile(
      "global_load_dwordx2 %0, %16, off sc0 sc1\n\t"
      "global_load_dwordx2 %1, %16, off offset:512 sc0 sc1\n\t"
      "global_load_dwordx2 %2, %16, off offset:1024 sc0 sc1\n\t"
      "global_load_dwordx2 %3, %16, off offset:1536 sc0 sc1\n\t"
      "global_load_dwordx2 %4, %16, off offset:2048 sc0 sc1\n\t"
      "global_load_dwordx2 %5, %16, off offset:2560 sc0 sc1\n\t"
      "global_load_dwordx2 %6, %16, off offset:3072 sc0 sc1\n\t"
      "global_load_dwordx2 %7, %16, off offset:3584 sc0 sc1\n\t"
      "global_load_dwordx2 %8, %17, off sc0 sc1\n\t"
      "global_load_dwordx2 %9, %17, off offset:512 sc0 sc1\n\t"
      "global_load_dwordx2 %10, %17, off offset:1024 sc0 sc1\n\t"
      "global_load_dwordx2 %11, %17, off offset:1536 sc0 sc1\n\t"
      "global_load_dwordx2 %12, %17, off offset:2048 sc0 sc1\n\t"
      "global_load_dwordx2 %13, %17, off offset:2560 sc0 sc1\n\t"
      "global_load_dwordx2 %14, %17, off offset:3072 sc0 sc1\n\t"
      "global_load_dwordx2 %15, %17, off offset:3584 sc0 sc1\n\t"
      "s_waitcnt vmcnt(0)"
      : "=&v"(a0),"=&v"(a1),"=&v"(a2),"=&v"(a3),"=&v"(a4),"=&v"(a5),"=&v"(a6),"=&v"(a7),
        "=&v"(a8),"=&v"(a9),"=&v"(aa),"=&v"(ab),"=&v"(ac),"=&v"(ad),"=&v"(ae),"=&v"(af)
      : "v"(p0), "v"(p1) : "memory");
    unsigned f = __float_as_uint(a0.y) & __float_as_uint(a1.y) & __float_as_uint(a2.y) &
                 __float_as_uint(a3.y) & __float_as_uint(a4.y) & __float_as_uint(a5.y) &
                 __float_as_uint(a6.y) & __float_as_uint(a7.y) & __float_as_uint(a8.y) &
                 __float_as_uint(a9.y) & __float_as_uint(aa.y) & __float_as_uint(ab.y) &
                 __float_as_uint(ac.y) & __float_as_uint(ad.y) & __float_as_uint(ae.y) &
                 __float_as_uint(af.y);
    if (__all(f == FLAGB)) break;
    __builtin_amdgcn_s_sleep(1);
  }
  dst[lane]        = a0.x;  dst[lane + 64]  = a1.x;  dst[lane + 128] = a2.x;
  dst[lane + 192]  = a3.x;  dst[lane + 256] = a4.x;  dst[lane + 320] = a5.x;
  dst[lane + 384]  = a6.x;  dst[lane + 448] = a7.x;  dst[lane + 512] = a8.x;
  dst[lane + 576]  = a9.x;  dst[lane + 640] = aa.x;  dst[lane + 704] = ab.x;
  dst[lane + 768]  = ac.x;  dst[lane + 832] = ad.x;  dst[lane + 896] = ae.x;
  dst[lane + 960]  = af.x;
}

// wave-0 poll of 512 flagged entries; lane l owns entries l+64k, k=0..7.
__device__ __forceinline__ void poll512(const unsigned long long* ent, float* dst, int lane) {
  const unsigned long long* p0 = ent + lane;
  float2 a0,a1,a2,a3,a4,a5,a6,a7;
  for (;;) {
    asm volatile(
      "global_load_dwordx2 %0, %8, off sc0 sc1\n\t"
      "global_load_dwordx2 %1, %8, off offset:512 sc0 sc1\n\t"
      "global_load_dwordx2 %2, %8, off offset:1024 sc0 sc1\n\t"
      "global_load_dwordx2 %3, %8, off offset:1536 sc0 sc1\n\t"
      "global_load_dwordx2 %4, %8, off offset:2048 sc0 sc1\n\t"
      "global_load_dwordx2 %5, %8, off offset:2560 sc0 sc1\n\t"
      "global_load_dwordx2 %6, %8, off offset:3072 sc0 sc1\n\t"
      "global_load_dwordx2 %7, %8, off offset:3584 sc0 sc1\n\t"
      "s_waitcnt vmcnt(0)"
      : "=&v"(a0),"=&v"(a1),"=&v"(a2),"=&v"(a3),"=&v"(a4),"=&v"(a5),"=&v"(a6),"=&v"(a7)
      : "v"(p0) : "memory");
    unsigned f = __float_as_uint(a0.y) & __float_as_uint(a1.y) & __float_as_uint(a2.y) &
                 __float_as_uint(a3.y) & __float_as_uint(a4.y) & __float_as_uint(a5.y) &
                 __float_as_uint(a6.y) & __float_as_uint(a7.y);
    if (__all(f == FLAGB)) break;
    __builtin_amdgcn_s_sleep(1);
  }
  dst[lane]       = a0.x;  dst[lane + 64]  = a1.x;  dst[lane + 128] = a2.x;
  dst[lane + 192] = a3.x;  dst[lane + 256] = a4.x;  dst[lane + 320] = a5.x;
  dst[lane + 384] = a6.x;  dst[lane + 448] = a7.x;
}

// 16 scalar weight loads (stride 256B) via one opaque asm block
__device__ __forceinline__ void gload16(const float* base, float* d) {
  asm volatile(
      "global_load_dword %0, %16, off\n\t"
      "global_load_dword %1, %16, off offset:256\n\t"
      "global_load_dword %2, %16, off offset:512\n\t"
      "global_load_dword %3, %16, off offset:768\n\t"
      "global_load_dword %4, %16, off offset:1024\n\t"
      "global_load_dword %5, %16, off offset:1280\n\t"
      "global_load_dword %6, %16, off offset:1536\n\t"
      "global_load_dword %7, %16, off offset:1792\n\t"
      "global_load_dword %8, %16, off offset:2048\n\t"
      "global_load_dword %9, %16, off offset:2304\n\t"
      "global_load_dword %10, %16, off offset:2560\n\t"
      "global_load_dword %11, %16, off offset:2816\n\t"
      "global_load_dword %12, %16, off offset:3072\n\t"
      "global_load_dword %13, %16, off offset:3328\n\t"
      "global_load_dword %14, %16, off offset:3584\n\t"
      "global_load_dword %15, %16, off offset:3840\n\t"
      "s_waitcnt vmcnt(0)"
      : "=&v"(d[0]), "=&v"(d[1]), "=&v"(d[2]), "=&v"(d[3]),
        "=&v"(d[4]), "=&v"(d[5]), "=&v"(d[6]), "=&v"(d[7]),
        "=&v"(d[8]), "=&v"(d[9]), "=&v"(d[10]), "=&v"(d[11]),
        "=&v"(d[12]), "=&v"(d[13]), "=&v"(d[14]), "=&v"(d[15])
      : "v"(base));
}

// ---------------- prep: gathers, bias sums, replica-mailbox init ------------
__global__ void prep_kernel(const int* __restrict__ word, const int* __restrict__ tense,
                            const float* __restrict__ tense_emb,
                            const float* __restrict__ enc_emb, const float* __restrict__ dec_emb,
                            const float* __restrict__ enc_bih, const float* __restrict__ enc_bhh,
                            const float* __restrict__ dec_bih, const float* __restrict__ dec_bhh,
                            float* __restrict__ ws, int R) {
  int gid = blockIdx.x * blockDim.x + threadIdx.x;
  int gsz = gridDim.x * blockDim.x;
  int tens = tense[0];
  for (int i = gid; i < Td * Hd; i += gsz) {
    int t = i >> 10, hh = i & 1023;
    ws[OFF_ENCX + i] = enc_emb[(size_t)word[t] * Hd + hh];
    int tok = (t == 0) ? 0 : word[t - 1];        // SOS = 0
    float v = dec_emb[(size_t)tok * Hd + hh];
    ws[OFF_DECX + i] = v > 0.f ? v : 0.f;        // relu
  }
  for (int i = gid; i < 4096; i += gsz) {
    ws[OFF_BSE + i] = enc_bih[i] + enc_bhh[i];
    ws[OFF_BSD + i] = dec_bih[i] + dec_bhh[i];
  }
  for (int i = gid; i < 32; i += gsz) ws[OFF_TEN + i] = tense_emb[tens * 32 + i];
  // replica mailboxes
  float2* rep = (float2*)(ws + OFF_REP);
  int total = R * (int)REP_ULL;
  for (int i = gid; i < total; i += gsz) {
    int e = i % (int)REP_ULL;
    float2 v;
    if (e < (int)HB_ULL) {
      int s = e >> 10, j = e & 1023;
      if (s == 0) {
        v.x = (j < Hd - 32) ? 0.f : tense_emb[tens * 32 + (j - (Hd - 32))];
        v.y = 1.0f;
      } else { v.x = 0.f; v.y = 0.f; }
    } else { v.x = 0.f; v.y = 0.f; }
    rep[i] = v;
  }
}

// ---------------- fp32 GEMM body: out[t][r] = x[t]·W[r] + bias[r] -----------
__device__ __forceinline__ void gemm_body(const float* __restrict__ W,
                                          const float* __restrict__ x,
                                          const float* __restrict__ bias,
                                          float* __restrict__ out, int R, int rbase) {
  __shared__ float xs[64][65];
  __shared__ float wsh[64][65];
  const int tid = threadIdx.x;
  const int a = tid >> 4;
  const int b = tid & 15;
  const int srow = tid >> 2;
  const int scol = (tid & 3) * 16;
  float acc[4][4];
#pragma unroll
  for (int i = 0; i < 4; ++i)
#pragma unroll
    for (int q = 0; q < 4; ++q) acc[i][q] = 0.f;

  for (int kc = 0; kc < 1024; kc += 64) {
    const float4* gx = (const float4*)(x + (size_t)srow * 1024 + kc + scol);
    const float4* gw = (const float4*)(W + (size_t)(rbase + srow) * 1024 + kc + scol);
    float4 vx0 = gx[0], vx1 = gx[1], vx2 = gx[2], vx3 = gx[3];
    float4 vw0 = gw[0], vw1 = gw[1], vw2 = gw[2], vw3 = gw[3];
    __syncthreads();
    float* xr = &xs[srow][scol];
    xr[0]=vx0.x; xr[1]=vx0.y; xr[2]=vx0.z; xr[3]=vx0.w;
    xr[4]=vx1.x; xr[5]=vx1.y; xr[6]=vx1.z; xr[7]=vx1.w;
    xr[8]=vx2.x; xr[9]=vx2.y; xr[10]=vx2.z; xr[11]=vx2.w;
    xr[12]=vx3.x; xr[13]=vx3.y; xr[14]=vx3.z; xr[15]=vx3.w;
    float* wr = &wsh[srow][scol];
    wr[0]=vw0.x; wr[1]=vw0.y; wr[2]=vw0.z; wr[3]=vw0.w;
    wr[4]=vw1.x; wr[5]=vw1.y; wr[6]=vw1.z; wr[7]=vw1.w;
    wr[8]=vw2.x; wr[9]=vw2.y; wr[10]=vw2.z; wr[11]=vw2.w;
    wr[12]=vw3.x; wr[13]=vw3.y; wr[14]=vw3.z; wr[15]=vw3.w;
    __syncthreads();
#pragma unroll 8
    for (int kk = 0; kk < 64; ++kk) {
      float xv[4], wv[4];
#pragma unroll
      for (int i = 0; i < 4; ++i) xv[i] = xs[a * 4 + i][kk];
#pragma unroll
      for (int q = 0; q < 4; ++q) wv[q] = wsh[b * 4 + q][kk];
#pragma unroll
      for (int i = 0; i < 4; ++i)
#pragma unroll
        for (int q = 0; q < 4; ++q) acc[i][q] = fmaf(xv[i], wv[q], acc[i][q]);
    }
  }
#pragma unroll
  for (int i = 0; i < 4; ++i) {
    int t = a * 4 + i;
#pragma unroll
    for (int q = 0; q < 4; ++q) {
      int r = rbase + b * 4 + q;
      out[(size_t)t * R + r] = acc[i][q] + bias[r];
    }
  }
}

__global__ __launch_bounds__(256) void gemm_kernel(const float* __restrict__ W,
                                                   const float* __restrict__ x,
                                                   const float* __restrict__ bias,
                                                   float* __restrict__ out, int R) {
  gemm_body(W, x, bias, out, R, blockIdx.x * 64);
}

__global__ __launch_bounds__(256) void gemm_dual_kernel(
    const float* __restrict__ W0, const float* __restrict__ x0,
    const float* __restrict__ b0, float* __restrict__ o0,
    const float* __restrict__ W1, const float* __restrict__ x1,
    const float* __restrict__ b1, float* __restrict__ o1) {
  if (blockIdx.x < 64) gemm_body(W0, x0, b0, o0, 4096, blockIdx.x * 64);
  else                 gemm_body(W1, x1, b1, o1, 4096, (blockIdx.x - 64) * 64);
}

// ---------------- persistent dataflow sequential kernel ---------------------
// 128 blocks x 512 threads; wave w of block b owns column j = b*8+w.
// Wave 0 polls replica (blockIdx % R); producers store to all R replicas.
__global__ __launch_bounds__(512, 2) void seq_kernel(
    const float* __restrict__ enc_Whh, const float* __restrict__ dec_Whh,
    const float* __restrict__ W_mean, const float* __restrict__ b_mean,
    const float* __restrict__ W_var, const float* __restrict__ b_var,
    const float* __restrict__ W_l2h, const float* __restrict__ b_l2h,
    const float* __restrict__ eps, float* __restrict__ ws, float* __restrict__ dout,
    int R) {
  __shared__ float hsbuf[2][Hd];
  __shared__ float sm2[512];
  __shared__ float lat[288];
  const int tid = threadIdx.x;
  const int lane = tid & 63;
  const int wid = tid >> 6;
  const int j = blockIdx.x * 8 + wid;          // 0..1023

  unsigned long long* rep0 = (unsigned long long*)(ws + OFF_REP);
  const unsigned long long* myrep = rep0 + (size_t)(blockIdx.x % R) * REP_ULL;
  const float* Genc = ws + OFF_GENC;
  const float* Gdec = ws + OFF_GDEC;
  float* h_all = ws + OFF_HALL;

  // ---- recurrent weights -> registers (opaque loads) ----
  float we[4][16], wd[4][16];
#pragma unroll
  for (int r = 0; r < 4; ++r) {
    const size_t ro = (size_t)(r * Hd + j) * Hd + lane;
    gload16(enc_Whh + ro, we[r]);
    gload16(dec_Whh + ro, wd[r]);
  }

  int pp = 0;
  // ---- encoder ----
  float c_reg = 0.f;
  for (int t = 0; t < Td; ++t) {
    float gb0 = Genc[t * 4096 + j];
    float gb1 = Genc[t * 4096 + 1024 + j];
    float gb2 = Genc[t * 4096 + 2048 + j];
    float gb3 = Genc[t * 4096 + 3072 + j];
    if (wid == 0) poll1024(myrep + (size_t)t * 1024, hsbuf[pp], lane);
    __syncthreads();
    const float* hs = hsbuf[pp]; pp ^= 1;
    float p0 = 0.f, p1 = 0.f, p2 = 0.f, p3 = 0.f;
#pragma unroll
    for (int i = 0; i < 16; ++i) {
      float hv = hs[lane + 64 * i];
      p0 = fmaf(we[0][i], hv, p0);
      p1 = fmaf(we[1][i], hv, p1);
      p2 = fmaf(we[2][i], hv, p2);
      p3 = fmaf(we[3][i], hv, p3);
    }
#pragma unroll
    for (int off = 32; off; off >>= 1) {
      p0 += __shfl_xor(p0, off, 64); p1 += __shfl_xor(p1, off, 64);
      p2 += __shfl_xor(p2, off, 64); p3 += __shfl_xor(p3, off, 64);
    }
    float gi = gb0 + p0, gf = gb1 + p1, gg = gb2 + p2, go = gb3 + p3;
    c_reg = fsigm(gf) * c_reg + fsigm(gi) * ftanh(gg);
    float hval = fsigm(go) * ftanh(c_reg);
    if (lane == 0) st_rep(rep0, (size_t)(t + 1) * 1024 + j, hval, R);
  }

  // ---- final encoder h ----
  if (wid == 0) poll1024(myrep + (size_t)64 * 1024, hsbuf[pp], lane);
  __syncthreads();
  const float* hfin = hsbuf[pp]; pp ^= 1;

  // ---- mean / logvar (waves owning j<512) ----
  if (j < 512) {
    const float* Wrow = (j < 256) ? (W_mean + (size_t)j * Hd) : (W_var + (size_t)(j - 256) * Hd);
    float p = 0.f;
#pragma unroll
    for (int i = 0; i < 16; ++i) p = fmaf(Wrow[lane + 64 * i], hfin[lane + 64 * i], p);
#pragma unroll
    for (int off = 32; off; off >>= 1) p += __shfl_xor(p, off, 64);
    if (lane == 0) {
      float v = p + ((j < 256) ? b_mean[j] : b_var[j - 256]);
      st_rep(rep0, (size_t)HB_ULL + j, v, R);
      dout[(j < 256) ? (2048064 + j) : (2048320 + (j - 256))] = v;
    }
  }

  // ---- poll mean/logvar, build [latent | tense] ----
  if (wid == 0) poll512(myrep + HB_ULL, sm2, lane);
  __syncthreads();
  if (tid < 256)      lat[tid] = sm2[tid] + eps[tid] * __expf(0.5f * sm2[tid + 256]);
  else if (tid < 288) lat[tid] = ws[OFF_TEN + tid - 256];
  __syncthreads();

  // ---- dec_h0[j] = W_l2h[j]·[latent|tense] + b ----
  {
    const float* Wr = W_l2h + (size_t)j * 288;
    float p = fmaf(Wr[lane], lat[lane], 0.f);
    p = fmaf(Wr[lane + 64], lat[lane + 64], p);
    p = fmaf(Wr[lane + 128], lat[lane + 128], p);
    p = fmaf(Wr[lane + 192], lat[lane + 192], p);
    if (lane < 32) p = fmaf(Wr[lane + 256], lat[lane + 256], p);
#pragma unroll
    for (int off = 32; off; off >>= 1) p += __shfl_xor(p, off, 64);
    if (lane == 0) st_rep(rep0, (size_t)65 * 1024 + j, p + b_l2h[j], R);
  }

  // ---- decoder ----
  c_reg = 0.f;
  for (int t = 0; t < Td; ++t) {
    float gb0 = Gdec[t * 4096 + j];
    float gb1 = Gdec[t * 4096 + 1024 + j];
    float gb2 = Gdec[t * 4096 + 2048 + j];
    float gb3 = Gdec[t * 4096 + 3072 + j];
    if (wid == 0) poll1024(myrep + (size_t)(65 + t) * 1024, hsbuf[pp], lane);
    __syncthreads();
    const float* hs = hsbuf[pp]; pp ^= 1;
    float p0 = 0.f, p1 = 0.f, p2 = 0.f, p3 = 0.f;
#pragma unroll
    for (int i = 0; i < 16; ++i) {
      float hv = hs[lane + 64 * i];
      p0 = fmaf(wd[0][i], hv, p0);
      p1 = fmaf(wd[1][i], hv, p1);
      p2 = fmaf(wd[2][i], hv, p2);
      p3 = fmaf(wd[3][i], hv, p3);
    }
#pragma unroll
    for (int off = 32; off; off >>= 1) {
      p0 += __shfl_xor(p0, off, 64); p1 += __shfl_xor(p1, off, 64);
      p2 += __shfl_xor(p2, off, 64); p3 += __shfl_xor(p3, off, 64);
    }
    float gi = gb0 + p0, gf = gb1 + p1, gg = gb2 + p2, go = gb3 + p3;
    c_reg = fsigm(gf) * c_reg + fsigm(gi) * ftanh(gg);
    float hval = fsigm(go) * ftanh(c_reg);
    if (lane == 0) {
      st_rep(rep0, (size_t)(66 + t) * 1024 + j, hval, R);
      h_all[(size_t)t * Hd + j] = hval;
    }
  }
}

// ---------------- fused per-row max/argmax/LSE + normalize -------------------
__global__ __launch_bounds__(1024) void logsm_kernel(float* __restrict__ out) {
  const int t = blockIdx.x, tid = threadIdx.x;
  float* row = out + 64 + (size_t)t * Vd;
  __shared__ float sm[1024];
  __shared__ int si[1024];
  float m = -INFINITY; int mi = 0;
  for (int v = tid; v < Vd; v += 1024) {
    float x = row[v];
    if (x > m) { m = x; mi = v; }
  }
  sm[tid] = m; si[tid] = mi;
  __syncthreads();
  for (int s = 512; s > 0; s >>= 1) {
    if (tid < s) {
      float om = sm[tid + s]; int oi = si[tid + s];
      if (om > sm[tid] || (om == sm[tid] && oi < si[tid])) { sm[tid] = om; si[tid] = oi; }
    }
    __syncthreads();
  }
  float rm = sm[0]; int ri = si[0];
  __syncthreads();
  float s = 0.f;
  for (int v = tid; v < Vd; v += 1024) s += __expf(row[v] - rm);
  sm[tid] = s;
  __syncthreads();
  for (int st = 512; st > 0; st >>= 1) {
    if (tid < st) sm[tid] += sm[tid + st];
    __syncthreads();
  }
  float corr = rm + logf(sm[0]);
  float4* r4 = (float4*)row;
  for (int i = tid; i < Vd / 4; i += 1024) {
    float4 v = r4[i];
    v.x -= corr; v.y -= corr; v.z -= corr; v.w -= corr;
    r4[i] = v;
  }
  if (tid == 0) out[t] = (float)ri;
}

extern "C" void kernel_launch(void* const* d_in, const int* in_sizes, int n_in,
                              void* d_out, int out_size, void* d_ws, size_t ws_size,
                              hipStream_t stream) {
  (void)in_sizes; (void)n_in; (void)out_size;
  const int* word       = (const int*)d_in[0];
  const int* tense      = (const int*)d_in[1];
  const float* tense_emb = (const float*)d_in[3];
  const float* enc_emb   = (const float*)d_in[4];
  const float* enc_Wih   = (const float*)d_in[5];
  const float* enc_Whh   = (const float*)d_in[6];
  const float* enc_bih   = (const float*)d_in[7];
  const float* enc_bhh   = (const float*)d_in[8];
  const float* W_mean    = (const float*)d_in[9];
  const float* b_mean    = (const float*)d_in[10];
  const float* W_var     = (const float*)d_in[11];
  const float* b_var     = (const float*)d_in[12];
  const float* W_l2h     = (const float*)d_in[13];
  const float* b_l2h     = (const float*)d_in[14];
  const float* dec_emb   = (const float*)d_in[15];
  const float* dec_Wih   = (const float*)d_in[16];
  const float* dec_Whh   = (const float*)d_in[17];
  const float* dec_bih   = (const float*)d_in[18];
  const float* dec_bhh   = (const float*)d_in[19];
  const float* W_out     = (const float*)d_in[20];
  const float* b_out     = (const float*)d_in[21];
  const float* eps       = (const float*)d_in[22];
  float* out = (float*)d_out;
  float* ws  = (float*)d_ws;

  // replica count from available workspace
  size_t avail = ws_size / 4;
  int R = 1;
  if (avail > OFF_REP + 2 * (size_t)REP_ULL * 2) {
    size_t r = (avail - OFF_REP) / (2 * (size_t)REP_ULL);
    R = (int)(r < 16 ? r : 16);
    if (R < 1) R = 1;
  }

  prep_kernel<<<1024, 256, 0, stream>>>(word, tense, tense_emb, enc_emb, dec_emb,
                                        enc_bih, enc_bhh, dec_bih, dec_bhh, ws, R);
  gemm_dual_kernel<<<128, 256, 0, stream>>>(enc_Wih, ws + OFF_ENCX, ws + OFF_BSE, ws + OFF_GENC,
                                            dec_Wih, ws + OFF_DECX, ws + OFF_BSD, ws + OFF_GDEC);
  seq_kernel<<<128, 512, 0, stream>>>(enc_Whh, dec_Whh, W_mean, b_mean, W_var, b_var,
                                      W_l2h, b_l2h, eps, ws, out, R);
  gemm_kernel<<<500, 256, 0, stream>>>(W_out, ws + OFF_HALL, b_out, out + 64, 32000);
  logsm_kernel<<<64, 1024, 0, stream>>>(out);
}

// Round 5
// 555.211 us; speedup vs baseline: 1.1409x; 1.1409x over previous
//
#include <hip/hip_runtime.h>
#include <math.h>

#define Hd 1024
#define Td 64
#define Vd 32000

// ---- static workspace float offsets ----
static const size_t OFF_ENCX  = 0;         // 64*1024
static const size_t OFF_DECX  = 65536;     // 64*1024
static const size_t OFF_GENC  = 131072;    // 64*4096
static const size_t OFF_GDEC  = 393216;    // 64*4096
static const size_t OFF_BSE   = 655360;    // 4096
static const size_t OFF_BSD   = 659456;    // 4096
static const size_t OFF_TEN   = 663552;    // 32
static const size_t OFF_HALL  = 663584;    // 64*1024 (ends 729120)
static const size_t OFF_STATS = 729120;    // 64*16 logsm partials (ends 730144)
static const size_t OFF_MB    = 730144;    // mailbox: 130*1024 + 256 float2 pairs

#define MB_H_PAIRS  133120u       // 130 slots x 1024 pairs
#define MB_PAIRS    133376u       // + 256 latent pairs
#define FLAGB       0x3f800000u

__device__ __forceinline__ float fsigm(float x) {
  return __fdividef(1.f, 1.f + __expf(-x));
}
__device__ __forceinline__ float ftanh(float x) {
  return 1.f - __fdividef(2.f, __expf(2.f * x) + 1.f);
}

__device__ __forceinline__ void st_flag(unsigned long long* p, float v) {
  unsigned long long u = 0x3f80000000000000ull | (unsigned long long)__float_as_uint(v);
  __hip_atomic_store(p, u, __ATOMIC_RELAXED, __HIP_MEMORY_SCOPE_AGENT);
}

// one 16B coherent poll load (two {value,flag} pairs); tight spin, no sleep
__device__ __forceinline__ float4 poll16(const float2* p) {
  float4 a;
  for (;;) {
    asm volatile("global_load_dwordx4 %0, %1, off sc0 sc1\n\ts_waitcnt vmcnt(0)"
                 : "=&v"(a) : "v"(p) : "memory");
    if (__float_as_uint(a.y) == FLAGB && __float_as_uint(a.w) == FLAGB) return a;
  }
}

// stage 1024 flagged entries (512 threads x 2) into LDS buffer; ONE sync
__device__ __forceinline__ void stage1024(const float2* base, float* dst, int tid) {
  float4 a = poll16(base + 2 * tid);
  ((float2*)dst)[tid] = make_float2(a.x, a.z);
  __syncthreads();
}

// ---------------- prep: gathers, bias sums, mailbox init --------------------
__global__ void prep_kernel(const int* __restrict__ word, const int* __restrict__ tense,
                            const float* __restrict__ tense_emb,
                            const float* __restrict__ enc_emb, const float* __restrict__ dec_emb,
                            const float* __restrict__ enc_bih, const float* __restrict__ enc_bhh,
                            const float* __restrict__ dec_bih, const float* __restrict__ dec_bhh,
                            float* __restrict__ ws) {
  int gid = blockIdx.x * blockDim.x + threadIdx.x;
  int gsz = gridDim.x * blockDim.x;
  int tens = tense[0];
  for (int i = gid; i < Td * Hd; i += gsz) {
    int t = i >> 10, hh = i & 1023;
    ws[OFF_ENCX + i] = enc_emb[(size_t)word[t] * Hd + hh];
    int tok = (t == 0) ? 0 : word[t - 1];        // SOS = 0
    float v = dec_emb[(size_t)tok * Hd + hh];
    ws[OFF_DECX + i] = v > 0.f ? v : 0.f;        // relu
  }
  for (int i = gid; i < 4096; i += gsz) {
    ws[OFF_BSE + i] = enc_bih[i] + enc_bhh[i];
    ws[OFF_BSD + i] = dec_bih[i] + dec_bhh[i];
  }
  for (int i = gid; i < 32; i += gsz) ws[OFF_TEN + i] = tense_emb[tens * 32 + i];
  float2* mb = (float2*)(ws + OFF_MB);
  for (int i = gid; i < (int)MB_PAIRS; i += gsz) {
    float2 v;
    if (i < (int)MB_H_PAIRS && (i >> 10) == 0) {
      int j = i & 1023;
      v.x = (j < Hd - 32) ? 0.f : tense_emb[tens * 32 + (j - (Hd - 32))];
      v.y = 1.0f;
    } else { v.x = 0.f; v.y = 0.f; }
    mb[i] = v;
  }
}

// ---------------- fp32 GEMM body: out[t][r] = x[t]·W[r] + bias[r] -----------
__device__ __forceinline__ void gemm_body(const float* __restrict__ W,
                                          const float* __restrict__ x,
                                          const float* __restrict__ bias,
                                          float* __restrict__ out, int R, int rbase) {
  __shared__ float xs[64][65];
  __shared__ float wsh[64][65];
  const int tid = threadIdx.x;
  const int a = tid >> 4;
  const int b = tid & 15;
  const int srow = tid >> 2;
  const int scol = (tid & 3) * 16;
  float acc[4][4];
#pragma unroll
  for (int i = 0; i < 4; ++i)
#pragma unroll
    for (int q = 0; q < 4; ++q) acc[i][q] = 0.f;

  for (int kc = 0; kc < 1024; kc += 64) {
    const float4* gx = (const float4*)(x + (size_t)srow * 1024 + kc + scol);
    const float4* gw = (const float4*)(W + (size_t)(rbase + srow) * 1024 + kc + scol);
    float4 vx0 = gx[0], vx1 = gx[1], vx2 = gx[2], vx3 = gx[3];
    float4 vw0 = gw[0], vw1 = gw[1], vw2 = gw[2], vw3 = gw[3];
    __syncthreads();
    float* xr = &xs[srow][scol];
    xr[0]=vx0.x; xr[1]=vx0.y; xr[2]=vx0.z; xr[3]=vx0.w;
    xr[4]=vx1.x; xr[5]=vx1.y; xr[6]=vx1.z; xr[7]=vx1.w;
    xr[8]=vx2.x; xr[9]=vx2.y; xr[10]=vx2.z; xr[11]=vx2.w;
    xr[12]=vx3.x; xr[13]=vx3.y; xr[14]=vx3.z; xr[15]=vx3.w;
    float* wr = &wsh[srow][scol];
    wr[0]=vw0.x; wr[1]=vw0.y; wr[2]=vw0.z; wr[3]=vw0.w;
    wr[4]=vw1.x; wr[5]=vw1.y; wr[6]=vw1.z; wr[7]=vw1.w;
    wr[8]=vw2.x; wr[9]=vw2.y; wr[10]=vw2.z; wr[11]=vw2.w;
    wr[12]=vw3.x; wr[13]=vw3.y; wr[14]=vw3.z; wr[15]=vw3.w;
    __syncthreads();
#pragma unroll 8
    for (int kk = 0; kk < 64; ++kk) {
      float xv[4], wv[4];
#pragma unroll
      for (int i = 0; i < 4; ++i) xv[i] = xs[a * 4 + i][kk];
#pragma unroll
      for (int q = 0; q < 4; ++q) wv[q] = wsh[b * 4 + q][kk];
#pragma unroll
      for (int i = 0; i < 4; ++i)
#pragma unroll
        for (int q = 0; q < 4; ++q) acc[i][q] = fmaf(xv[i], wv[q], acc[i][q]);
    }
  }
#pragma unroll
  for (int i = 0; i < 4; ++i) {
    int t = a * 4 + i;
#pragma unroll
    for (int q = 0; q < 4; ++q) {
      int r = rbase + b * 4 + q;
      out[(size_t)t * R + r] = acc[i][q] + bias[r];
    }
  }
}

__global__ __launch_bounds__(256) void gemm_kernel(const float* __restrict__ W,
                                                   const float* __restrict__ x,
                                                   const float* __restrict__ bias,
                                                   float* __restrict__ out, int R) {
  gemm_body(W, x, bias, out, R, blockIdx.x * 64);
}

__global__ __launch_bounds__(256) void gemm_dual_kernel(
    const float* __restrict__ W0, const float* __restrict__ x0,
    const float* __restrict__ b0, float* __restrict__ o0,
    const float* __restrict__ W1, const float* __restrict__ x1,
    const float* __restrict__ b1, float* __restrict__ o1) {
  if (blockIdx.x < 64) gemm_body(W0, x0, b0, o0, 4096, blockIdx.x * 64);
  else                 gemm_body(W1, x1, b1, o1, 4096, (blockIdx.x - 64) * 64);
}

// 16 scalar weight loads (stride 256B) via one opaque asm block
__device__ __forceinline__ void gload16(const float* base, float* d) {
  asm volatile(
      "global_load_dword %0, %16, off\n\t"
      "global_load_dword %1, %16, off offset:256\n\t"
      "global_load_dword %2, %16, off offset:512\n\t"
      "global_load_dword %3, %16, off offset:768\n\t"
      "global_load_dword %4, %16, off offset:1024\n\t"
      "global_load_dword %5, %16, off offset:1280\n\t"
      "global_load_dword %6, %16, off offset:1536\n\t"
      "global_load_dword %7, %16, off offset:1792\n\t"
      "global_load_dword %8, %16, off offset:2048\n\t"
      "global_load_dword %9, %16, off offset:2304\n\t"
      "global_load_dword %10, %16, off offset:2560\n\t"
      "global_load_dword %11, %16, off offset:2816\n\t"
      "global_load_dword %12, %16, off offset:3072\n\t"
      "global_load_dword %13, %16, off offset:3328\n\t"
      "global_load_dword %14, %16, off offset:3584\n\t"
      "global_load_dword %15, %16, off offset:3840\n\t"
      "s_waitcnt vmcnt(0)"
      : "=&v"(d[0]), "=&v"(d[1]), "=&v"(d[2]), "=&v"(d[3]),
        "=&v"(d[4]), "=&v"(d[5]), "=&v"(d[6]), "=&v"(d[7]),
        "=&v"(d[8]), "=&v"(d[9]), "=&v"(d[10]), "=&v"(d[11]),
        "=&v"(d[12]), "=&v"(d[13]), "=&v"(d[14]), "=&v"(d[15])
      : "v"(base));
}

// ---------------- persistent dataflow sequential kernel ---------------------
// 128 blocks x 512 threads; wave w of block b owns column j = b*8+w.
__global__ __launch_bounds__(512, 2) void seq_kernel(
    const float* __restrict__ enc_Whh, const float* __restrict__ dec_Whh,
    const float* __restrict__ W_mean, const float* __restrict__ b_mean,
    const float* __restrict__ W_var, const float* __restrict__ b_var,
    const float* __restrict__ W_l2h, const float* __restrict__ b_l2h,
    const float* __restrict__ eps, float* __restrict__ ws, float* __restrict__ dout) {
  __shared__ float hsbuf[2][Hd];
  __shared__ float lat[288];
  const int tid = threadIdx.x;
  const int lane = tid & 63;
  const int wid = tid >> 6;
  const int j = blockIdx.x * 8 + wid;          // 0..1023

  float2* mb = (float2*)(ws + OFF_MB);
  unsigned long long* mbq = (unsigned long long*)(ws + OFF_MB);
  const float* Genc = ws + OFF_GENC;
  const float* Gdec = ws + OFF_GDEC;
  float* h_all = ws + OFF_HALL;

  // ---- recurrent weights -> on-chip registers ----
  float we[4][16], wd[4][16];
#pragma unroll
  for (int r = 0; r < 4; ++r) {
    const size_t ro = (size_t)(r * Hd + j) * Hd + lane;
    gload16(enc_Whh + ro, we[r]);
    gload16(dec_Whh + ro, wd[r]);
  }

  // ---- encoder ----
  float c_reg = 0.f;
  float gb0 = Genc[j], gb1 = Genc[1024 + j], gb2 = Genc[2048 + j], gb3 = Genc[3072 + j];
  for (int t = 0; t < Td; ++t) {
    stage1024(mb + (size_t)t * 1024, hsbuf[t & 1], tid);
    const float* hs = hsbuf[t & 1];
    float p0 = 0.f, p1 = 0.f, p2 = 0.f, p3 = 0.f;
#pragma unroll
    for (int i = 0; i < 16; ++i) {
      float hv = hs[lane + 64 * i];
      p0 = fmaf(we[0][i], hv, p0);
      p1 = fmaf(we[1][i], hv, p1);
      p2 = fmaf(we[2][i], hv, p2);
      p3 = fmaf(we[3][i], hv, p3);
    }
#pragma unroll
    for (int off = 32; off; off >>= 1) {
      p0 += __shfl_xor(p0, off, 64); p1 += __shfl_xor(p1, off, 64);
      p2 += __shfl_xor(p2, off, 64); p3 += __shfl_xor(p3, off, 64);
    }
    float gi = gb0 + p0, gf = gb1 + p1, gg = gb2 + p2, go = gb3 + p3;
    c_reg = fsigm(gf) * c_reg + fsigm(gi) * ftanh(gg);
    float hval = fsigm(go) * ftanh(c_reg);
    if (lane == 0) st_flag(mbq + (size_t)(t + 1) * 1024 + j, hval);
    if (t + 1 < Td) {       // off-chain prefetch; drained by next poll's vmcnt(0)
      gb0 = Genc[(t + 1) * 4096 + j];
      gb1 = Genc[(t + 1) * 4096 + 1024 + j];
      gb2 = Genc[(t + 1) * 4096 + 2048 + j];
      gb3 = Genc[(t + 1) * 4096 + 3072 + j];
    }
  }

  // ---- mean/logvar + latent, fused in producer waves (blocks 0..31) ----
  if (j < 256) {
    stage1024(mb + (size_t)Td * 1024, hsbuf[0], tid);
    const float* hs = hsbuf[0];
    const float* Wm = W_mean + (size_t)j * Hd;
    const float* Wv = W_var + (size_t)j * Hd;
    float pm = 0.f, pv = 0.f;
#pragma unroll
    for (int i = 0; i < 16; ++i) {
      float hv = hs[lane + 64 * i];
      pm = fmaf(Wm[lane + 64 * i], hv, pm);
      pv = fmaf(Wv[lane + 64 * i], hv, pv);
    }
#pragma unroll
    for (int off = 32; off; off >>= 1) {
      pm += __shfl_xor(pm, off, 64); pv += __shfl_xor(pv, off, 64);
    }
    if (lane == 0) {
      float m = pm + b_mean[j];
      float lv = pv + b_var[j];
      dout[2048064 + j] = m;
      dout[2048320 + j] = lv;
      float latv = m + eps[j] * __expf(0.5f * lv);
      st_flag(mbq + MB_H_PAIRS + j, latv);
    }
  }

  // ---- poll latent, build [latent | tense] in LDS ----
  if (tid < 128) {
    float4 a = poll16(mb + MB_H_PAIRS + 2 * tid);
    lat[2 * tid] = a.x; lat[2 * tid + 1] = a.z;
  } else if (tid < 160) {
    lat[256 + (tid - 128)] = ws[OFF_TEN + (tid - 128)];
  }
  __syncthreads();

  // ---- dec_h0[j] = W_l2h[j]·[latent|tense] + b ----
  {
    const float* Wr = W_l2h + (size_t)j * 288;
    float p = fmaf(Wr[lane], lat[lane], 0.f);
    p = fmaf(Wr[lane + 64], lat[lane + 64], p);
    p = fmaf(Wr[lane + 128], lat[lane + 128], p);
    p = fmaf(Wr[lane + 192], lat[lane + 192], p);
    if (lane < 32) p = fmaf(Wr[lane + 256], lat[lane + 256], p);
#pragma unroll
    for (int off = 32; off; off >>= 1) p += __shfl_xor(p, off, 64);
    if (lane == 0) st_flag(mbq + (size_t)65 * 1024 + j, p + b_l2h[j]);
  }
  __syncthreads();   // all lat reads done before decoder reuses hsbuf

  // ---- decoder ----
  c_reg = 0.f;
  gb0 = Gdec[j]; gb1 = Gdec[1024 + j]; gb2 = Gdec[2048 + j]; gb3 = Gdec[3072 + j];
  for (int t = 0; t < Td; ++t) {
    stage1024(mb + (size_t)(65 + t) * 1024, hsbuf[t & 1], tid);
    const float* hs = hsbuf[t & 1];
    float p0 = 0.f, p1 = 0.f, p2 = 0.f, p3 = 0.f;
#pragma unroll
    for (int i = 0; i < 16; ++i) {
      float hv = hs[lane + 64 * i];
      p0 = fmaf(wd[0][i], hv, p0);
      p1 = fmaf(wd[1][i], hv, p1);
      p2 = fmaf(wd[2][i], hv, p2);
      p3 = fmaf(wd[3][i], hv, p3);
    }
#pragma unroll
    for (int off = 32; off; off >>= 1) {
      p0 += __shfl_xor(p0, off, 64); p1 += __shfl_xor(p1, off, 64);
      p2 += __shfl_xor(p2, off, 64); p3 += __shfl_xor(p3, off, 64);
    }
    float gi = gb0 + p0, gf = gb1 + p1, gg = gb2 + p2, go = gb3 + p3;
    c_reg = fsigm(gf) * c_reg + fsigm(gi) * ftanh(gg);
    float hval = fsigm(go) * ftanh(c_reg);
    if (lane == 0) {
      if (t + 1 < Td) st_flag(mbq + (size_t)(66 + t) * 1024 + j, hval);
      h_all[(size_t)t * Hd + j] = hval;
    }
    if (t + 1 < Td) {
      gb0 = Gdec[(t + 1) * 4096 + j];
      gb1 = Gdec[(t + 1) * 4096 + 1024 + j];
      gb2 = Gdec[(t + 1) * 4096 + 2048 + j];
      gb3 = Gdec[(t + 1) * 4096 + 3072 + j];
    }
  }
}

// ---------------- log-softmax stats: per quarter-row {max, argmax, sumexp} --
__global__ __launch_bounds__(256) void lstats_kernel(const float* __restrict__ logits,
                                                     float* __restrict__ sd) {
  const int blk = blockIdx.x, t = blk >> 2, q = blk & 3, tid = threadIdx.x;
  const float* row = logits + (size_t)t * Vd + q * 8000;
  __shared__ float sm[256];
  __shared__ int si[256];
  float m = -INFINITY; int mi = 0x7fffffff;
  for (int v = tid; v < 8000; v += 256) {
    float x = row[v];
    if (x > m) { m = x; mi = v; }
  }
  sm[tid] = m; si[tid] = mi;
  __syncthreads();
  for (int s = 128; s > 0; s >>= 1) {
    if (tid < s) {
      float om = sm[tid + s]; int oi = si[tid + s];
      if (om > sm[tid] || (om == sm[tid] && oi < si[tid])) { sm[tid] = om; si[tid] = oi; }
    }
    __syncthreads();
  }
  float rm = sm[0]; int ri = si[0];
  __syncthreads();
  float s = 0.f;
  for (int v = tid; v < 8000; v += 256) s += __expf(row[v] - rm);
  sm[tid] = s;
  __syncthreads();
  for (int st = 128; st > 0; st >>= 1) {
    if (tid < st) sm[tid] += sm[tid + st];
    __syncthreads();
  }
  if (tid == 0) {
    sd[blk * 4 + 0] = rm;
    sd[blk * 4 + 1] = (float)(ri + q * 8000);
    sd[blk * 4 + 2] = sm[0];
  }
}

// ---------------- combine + normalize quarter-row ----------------------------
__global__ __launch_bounds__(256) void lfin_kernel(float* __restrict__ out,
                                                   const float* __restrict__ sd) {
  const int blk = blockIdx.x, t = blk >> 2, q = blk & 3, tid = threadIdx.x;
  float M = -INFINITY;
#pragma unroll
  for (int k = 0; k < 4; ++k) M = fmaxf(M, sd[t * 16 + k * 4]);
  float S = 0.f;
#pragma unroll
  for (int k = 0; k < 4; ++k) S += sd[t * 16 + k * 4 + 2] * __expf(sd[t * 16 + k * 4] - M);
  float corr = M + logf(S);
  float4* r4 = (float4*)(out + 64 + (size_t)t * Vd + q * 8000);
  for (int i = tid; i < 2000; i += 256) {
    float4 v = r4[i];
    v.x -= corr; v.y -= corr; v.z -= corr; v.w -= corr;
    r4[i] = v;
  }
  if (q == 0 && tid == 0) {
    float bm = -INFINITY; int bi = 0;
#pragma unroll
    for (int k = 0; k < 4; ++k) {
      float m = sd[t * 16 + k * 4];
      if (m > bm) { bm = m; bi = (int)sd[t * 16 + k * 4 + 1]; }
    }
    out[t] = (float)bi;
  }
}

extern "C" void kernel_launch(void* const* d_in, const int* in_sizes, int n_in,
                              void* d_out, int out_size, void* d_ws, size_t ws_size,
                              hipStream_t stream) {
  (void)in_sizes; (void)n_in; (void)out_size; (void)ws_size;
  const int* word       = (const int*)d_in[0];
  const int* tense      = (const int*)d_in[1];
  const float* tense_emb = (const float*)d_in[3];
  const float* enc_emb   = (const float*)d_in[4];
  const float* enc_Wih   = (const float*)d_in[5];
  const float* enc_Whh   = (const float*)d_in[6];
  const float* enc_bih   = (const float*)d_in[7];
  const float* enc_bhh   = (const float*)d_in[8];
  const float* W_mean    = (const float*)d_in[9];
  const float* b_mean    = (const float*)d_in[10];
  const float* W_var     = (const float*)d_in[11];
  const float* b_var     = (const float*)d_in[12];
  const float* W_l2h     = (const float*)d_in[13];
  const float* b_l2h     = (const float*)d_in[14];
  const float* dec_emb   = (const float*)d_in[15];
  const float* dec_Wih   = (const float*)d_in[16];
  const float* dec_Whh   = (const float*)d_in[17];
  const float* dec_bih   = (const float*)d_in[18];
  const float* dec_bhh   = (const float*)d_in[19];
  const float* W_out     = (const float*)d_in[20];
  const float* b_out     = (const float*)d_in[21];
  const float* eps       = (const float*)d_in[22];
  float* out = (float*)d_out;
  float* ws  = (float*)d_ws;

  prep_kernel<<<512, 256, 0, stream>>>(word, tense, tense_emb, enc_emb, dec_emb,
                                       enc_bih, enc_bhh, dec_bih, dec_bhh, ws);
  gemm_dual_kernel<<<128, 256, 0, stream>>>(enc_Wih, ws + OFF_ENCX, ws + OFF_BSE, ws + OFF_GENC,
                                            dec_Wih, ws + OFF_DECX, ws + OFF_BSD, ws + OFF_GDEC);
  seq_kernel<<<128, 512, 0, stream>>>(enc_Whh, dec_Whh, W_mean, b_mean, W_var, b_var,
                                      W_l2h, b_l2h, eps, ws, out);
  gemm_kernel<<<500, 256, 0, stream>>>(W_out, ws + OFF_HALL, b_out, out + 64, 32000);
  lstats_kernel<<<256, 256, 0, stream>>>(out + 64, ws + OFF_STATS);
  lfin_kernel<<<256, 256, 0, stream>>>(out, ws + OFF_STATS);
}

// Round 7
// 519.006 us; speedup vs baseline: 1.2205x; 1.0698x over previous
//
#include <hip/hip_runtime.h>
#include <math.h>

#define Hd 1024
#define Td 64
#define Vd 32000

// ---- static workspace float offsets ----
static const size_t OFF_ENCX  = 0;         // 64*1024
static const size_t OFF_DECX  = 65536;     // 64*1024
static const size_t OFF_GENC  = 131072;    // 64*4096
static const size_t OFF_GDEC  = 393216;    // 64*4096
static const size_t OFF_BSE   = 655360;    // 4096
static const size_t OFF_BSD   = 659456;    // 4096
static const size_t OFF_TEN   = 663552;    // 32
static const size_t OFF_HALL  = 663584;    // 64*1024 (ends 729120)
static const size_t OFF_STATS = 729120;    // 64*16 logsm partials (ends 730144)
static const size_t OFF_MB    = 730144;    // mailbox: 130*1024 + 256 float2 pairs

#define MB_H_PAIRS  133120u       // 130 slots x 1024 pairs
#define MB_PAIRS    133376u       // + 256 latent pairs
#define FLAGB       0x3f800000u

__device__ __forceinline__ float fsigm(float x) {
  return __fdividef(1.f, 1.f + __expf(-x));
}
__device__ __forceinline__ float ftanh(float x) {
  return 1.f - __fdividef(2.f, __expf(2.f * x) + 1.f);
}

// PROVEN transport (R3-R5): system-coherent sc0 sc1 flagged store
__device__ __forceinline__ void st_flag(unsigned long long* p, float v) {
  unsigned long long u = 0x3f80000000000000ull | (unsigned long long)__float_as_uint(v);
  __hip_atomic_store(p, u, __ATOMIC_RELAXED, __HIP_MEMORY_SCOPE_AGENT);
}

// one 16B coherent poll load (two {value,flag} pairs); tight spin, no sleep
__device__ __forceinline__ float4 poll16(const float2* p) {
  float4 a;
  for (;;) {
    asm volatile("global_load_dwordx4 %0, %1, off sc0 sc1\n\ts_waitcnt vmcnt(0)"
                 : "=&v"(a) : "v"(p) : "memory");
    if (__float_as_uint(a.y) == FLAGB && __float_as_uint(a.w) == FLAGB) return a;
  }
}

// stage 1024 flagged entries (512 threads x 2) into LDS buffer; ONE sync
__device__ __forceinline__ void stage1024(const float2* base, float* dst, int tid) {
  float4 a = poll16(base + 2 * tid);
  ((float2*)dst)[tid] = make_float2(a.x, a.z);
  __syncthreads();
}

// ---------------- prep: gathers, bias sums, mailbox init --------------------
__global__ void prep_kernel(const int* __restrict__ word, const int* __restrict__ tense,
                            const float* __restrict__ tense_emb,
                            const float* __restrict__ enc_emb, const float* __restrict__ dec_emb,
                            const float* __restrict__ enc_bih, const float* __restrict__ enc_bhh,
                            const float* __restrict__ dec_bih, const float* __restrict__ dec_bhh,
                            float* __restrict__ ws) {
  int gid = blockIdx.x * blockDim.x + threadIdx.x;
  int gsz = gridDim.x * blockDim.x;
  int tens = tense[0];
  for (int i = gid; i < Td * Hd; i += gsz) {
    int t = i >> 10, hh = i & 1023;
    ws[OFF_ENCX + i] = enc_emb[(size_t)word[t] * Hd + hh];
    int tok = (t == 0) ? 0 : word[t - 1];        // SOS = 0
    float v = dec_emb[(size_t)tok * Hd + hh];
    ws[OFF_DECX + i] = v > 0.f ? v : 0.f;        // relu
  }
  for (int i = gid; i < 4096; i += gsz) {
    ws[OFF_BSE + i] = enc_bih[i] + enc_bhh[i];
    ws[OFF_BSD + i] = dec_bih[i] + dec_bhh[i];
  }
  for (int i = gid; i < 32; i += gsz) ws[OFF_TEN + i] = tense_emb[tens * 32 + i];
  float2* mb = (float2*)(ws + OFF_MB);
  for (int i = gid; i < (int)MB_PAIRS; i += gsz) {
    float2 v;
    if (i < (int)MB_H_PAIRS && (i >> 10) == 0) {
      int j = i & 1023;
      v.x = (j < Hd - 32) ? 0.f : tense_emb[tens * 32 + (j - (Hd - 32))];
      v.y = 1.0f;
    } else { v.x = 0.f; v.y = 0.f; }
    mb[i] = v;
  }
}

// ---------------- fp32 GEMM: out[t][r] = x[t]·W[r] + bias[r] ----------------
// Transposed-LDS staging (xs[k][t], wsh[k][r]) -> inner loop is 2x ds_read_b128
// per 16 FMA. Tile 64x64, 256 threads, 4x4/thread, 2 blocks/CU.
__device__ __forceinline__ void gemm_body(const float* __restrict__ W,
                                          const float* __restrict__ x,
                                          const float* __restrict__ bias,
                                          float* __restrict__ out, int R, int rbase) {
  __shared__ float xs[64][68];    // [k][t], pad 68 keeps 16B alignment
  __shared__ float wsh[64][68];   // [k][r]
  const int tid = threadIdx.x;
  const int a = tid >> 4;         // 0..15 -> t group of 4  (FIXED: was (tid>>4)&3)
  const int b = tid & 15;         // 0..15 -> r group of 4
  const int sr = tid & 63;        // staging row (t or r) = lane
  const int kq = (tid >> 6) << 4; // staging k-offset: 0,16,32,48 (wave-uniform)
  float acc[4][4];
#pragma unroll
  for (int i = 0; i < 4; ++i)
#pragma unroll
    for (int q = 0; q < 4; ++q) acc[i][q] = 0.f;

  for (int kc = 0; kc < 1024; kc += 64) {
    const float4* gx = (const float4*)(x + (size_t)sr * 1024 + kc + kq);
    const float4* gw = (const float4*)(W + (size_t)(rbase + sr) * 1024 + kc + kq);
    float4 vx0 = gx[0], vx1 = gx[1], vx2 = gx[2], vx3 = gx[3];
    float4 vw0 = gw[0], vw1 = gw[1], vw2 = gw[2], vw3 = gw[3];
    __syncthreads();   // previous tile fully consumed
    xs[kq +  0][sr] = vx0.x; xs[kq +  1][sr] = vx0.y; xs[kq +  2][sr] = vx0.z; xs[kq +  3][sr] = vx0.w;
    xs[kq +  4][sr] = vx1.x; xs[kq +  5][sr] = vx1.y; xs[kq +  6][sr] = vx1.z; xs[kq +  7][sr] = vx1.w;
    xs[kq +  8][sr] = vx2.x; xs[kq +  9][sr] = vx2.y; xs[kq + 10][sr] = vx2.z; xs[kq + 11][sr] = vx2.w;
    xs[kq + 12][sr] = vx3.x; xs[kq + 13][sr] = vx3.y; xs[kq + 14][sr] = vx3.z; xs[kq + 15][sr] = vx3.w;
    wsh[kq +  0][sr] = vw0.x; wsh[kq +  1][sr] = vw0.y; wsh[kq +  2][sr] = vw0.z; wsh[kq +  3][sr] = vw0.w;
    wsh[kq +  4][sr] = vw1.x; wsh[kq +  5][sr] = vw1.y; wsh[kq +  6][sr] = vw1.z; wsh[kq +  7][sr] = vw1.w;
    wsh[kq +  8][sr] = vw2.x; wsh[kq +  9][sr] = vw2.y; wsh[kq + 10][sr] = vw2.z; wsh[kq + 11][sr] = vw2.w;
    wsh[kq + 12][sr] = vw3.x; wsh[kq + 13][sr] = vw3.y; wsh[kq + 14][sr] = vw3.z; wsh[kq + 15][sr] = vw3.w;
    __syncthreads();
#pragma unroll 8
    for (int kk = 0; kk < 64; ++kk) {
      float4 xv = *(const float4*)&xs[kk][a * 4];
      float4 wv = *(const float4*)&wsh[kk][b * 4];
      acc[0][0] = fmaf(xv.x, wv.x, acc[0][0]); acc[0][1] = fmaf(xv.x, wv.y, acc[0][1]);
      acc[0][2] = fmaf(xv.x, wv.z, acc[0][2]); acc[0][3] = fmaf(xv.x, wv.w, acc[0][3]);
      acc[1][0] = fmaf(xv.y, wv.x, acc[1][0]); acc[1][1] = fmaf(xv.y, wv.y, acc[1][1]);
      acc[1][2] = fmaf(xv.y, wv.z, acc[1][2]); acc[1][3] = fmaf(xv.y, wv.w, acc[1][3]);
      acc[2][0] = fmaf(xv.z, wv.x, acc[2][0]); acc[2][1] = fmaf(xv.z, wv.y, acc[2][1]);
      acc[2][2] = fmaf(xv.z, wv.z, acc[2][2]); acc[2][3] = fmaf(xv.z, wv.w, acc[2][3]);
      acc[3][0] = fmaf(xv.w, wv.x, acc[3][0]); acc[3][1] = fmaf(xv.w, wv.y, acc[3][1]);
      acc[3][2] = fmaf(xv.w, wv.z, acc[3][2]); acc[3][3] = fmaf(xv.w, wv.w, acc[3][3]);
    }
  }
  const int rb = rbase + b * 4;
  float4 bv = *(const float4*)(bias + rb);
#pragma unroll
  for (int i = 0; i < 4; ++i) {
    int t = a * 4 + i;
    float4 o;
    o.x = acc[i][0] + bv.x; o.y = acc[i][1] + bv.y;
    o.z = acc[i][2] + bv.z; o.w = acc[i][3] + bv.w;
    *(float4*)(out + (size_t)t * R + rb) = o;
  }
}

__global__ __launch_bounds__(256, 2) void gemm_kernel(const float* __restrict__ W,
                                                      const float* __restrict__ x,
                                                      const float* __restrict__ bias,
                                                      float* __restrict__ out, int R) {
  gemm_body(W, x, bias, out, R, blockIdx.x * 64);
}

__global__ __launch_bounds__(256, 2) void gemm_dual_kernel(
    const float* __restrict__ W0, const float* __restrict__ x0,
    const float* __restrict__ b0, float* __restrict__ o0,
    const float* __restrict__ W1, const float* __restrict__ x1,
    const float* __restrict__ b1, float* __restrict__ o1) {
  if (blockIdx.x < 64) gemm_body(W0, x0, b0, o0, 4096, blockIdx.x * 64);
  else                 gemm_body(W1, x1, b1, o1, 4096, (blockIdx.x - 64) * 64);
}

// 16 scalar weight loads (stride 256B) via one opaque asm block
__device__ __forceinline__ void gload16(const float* base, float* d) {
  asm volatile(
      "global_load_dword %0, %16, off\n\t"
      "global_load_dword %1, %16, off offset:256\n\t"
      "global_load_dword %2, %16, off offset:512\n\t"
      "global_load_dword %3, %16, off offset:768\n\t"
      "global_load_dword %4, %16, off offset:1024\n\t"
      "global_load_dword %5, %16, off offset:1280\n\t"
      "global_load_dword %6, %16, off offset:1536\n\t"
      "global_load_dword %7, %16, off offset:1792\n\t"
      "global_load_dword %8, %16, off offset:2048\n\t"
      "global_load_dword %9, %16, off offset:2304\n\t"
      "global_load_dword %10, %16, off offset:2560\n\t"
      "global_load_dword %11, %16, off offset:2816\n\t"
      "global_load_dword %12, %16, off offset:3072\n\t"
      "global_load_dword %13, %16, off offset:3328\n\t"
      "global_load_dword %14, %16, off offset:3584\n\t"
      "global_load_dword %15, %16, off offset:3840\n\t"
      "s_waitcnt vmcnt(0)"
      : "=&v"(d[0]), "=&v"(d[1]), "=&v"(d[2]), "=&v"(d[3]),
        "=&v"(d[4]), "=&v"(d[5]), "=&v"(d[6]), "=&v"(d[7]),
        "=&v"(d[8]), "=&v"(d[9]), "=&v"(d[10]), "=&v"(d[11]),
        "=&v"(d[12]), "=&v"(d[13]), "=&v"(d[14]), "=&v"(d[15])
      : "v"(base));
}

// ---------------- persistent dataflow sequential kernel ---------------------
// 128 blocks x 512 threads; wave w of block b owns column j = b*8+w.
__global__ __launch_bounds__(512, 2) void seq_kernel(
    const float* __restrict__ enc_Whh, const float* __restrict__ dec_Whh,
    const float* __restrict__ W_mean, const float* __restrict__ b_mean,
    const float* __restrict__ W_var, const float* __restrict__ b_var,
    const float* __restrict__ W_l2h, const float* __restrict__ b_l2h,
    const float* __restrict__ eps, float* __restrict__ ws, float* __restrict__ dout) {
  __shared__ float hsbuf[2][Hd];
  __shared__ float lat[288];
  const int tid = threadIdx.x;
  const int lane = tid & 63;
  const int wid = tid >> 6;
  const int j = blockIdx.x * 8 + wid;          // 0..1023

  float2* mb = (float2*)(ws + OFF_MB);
  unsigned long long* mbq = (unsigned long long*)(ws + OFF_MB);
  const float* Genc = ws + OFF_GENC;
  const float* Gdec = ws + OFF_GDEC;
  float* h_all = ws + OFF_HALL;

  // ---- recurrent weights -> on-chip registers ----
  float we[4][16], wd[4][16];
#pragma unroll
  for (int r = 0; r < 4; ++r) {
    const size_t ro = (size_t)(r * Hd + j) * Hd + lane;
    gload16(enc_Whh + ro, we[r]);
    gload16(dec_Whh + ro, wd[r]);
  }

  // ---- encoder ----
  float c_reg = 0.f;
  float gb0 = Genc[j], gb1 = Genc[1024 + j], gb2 = Genc[2048 + j], gb3 = Genc[3072 + j];
  for (int t = 0; t < Td; ++t) {
    stage1024(mb + (size_t)t * 1024, hsbuf[t & 1], tid);
    const float* hs = hsbuf[t & 1];
    float p0 = 0.f, p1 = 0.f, p2 = 0.f, p3 = 0.f;
#pragma unroll
    for (int i = 0; i < 16; ++i) {
      float hv = hs[lane + 64 * i];
      p0 = fmaf(we[0][i], hv, p0);
      p1 = fmaf(we[1][i], hv, p1);
      p2 = fmaf(we[2][i], hv, p2);
      p3 = fmaf(we[3][i], hv, p3);
    }
#pragma unroll
    for (int off = 32; off; off >>= 1) {
      p0 += __shfl_xor(p0, off, 64); p1 += __shfl_xor(p1, off, 64);
      p2 += __shfl_xor(p2, off, 64); p3 += __shfl_xor(p3, off, 64);
    }
    float gi = gb0 + p0, gf = gb1 + p1, gg = gb2 + p2, go = gb3 + p3;
    c_reg = fsigm(gf) * c_reg + fsigm(gi) * ftanh(gg);
    float hval = fsigm(go) * ftanh(c_reg);
    if (lane == 0) st_flag(mbq + (size_t)(t + 1) * 1024 + j, hval);
    if (t + 1 < Td) {       // off-chain prefetch; drained by next poll's vmcnt(0)
      gb0 = Genc[(t + 1) * 4096 + j];
      gb1 = Genc[(t + 1) * 4096 + 1024 + j];
      gb2 = Genc[(t + 1) * 4096 + 2048 + j];
      gb3 = Genc[(t + 1) * 4096 + 3072 + j];
    }
  }

  // ---- mean/logvar + latent, fused in producer waves (blocks 0..31) ----
  if (j < 256) {
    stage1024(mb + (size_t)Td * 1024, hsbuf[0], tid);
    const float* hs = hsbuf[0];
    const float* Wm = W_mean + (size_t)j * Hd;
    const float* Wv = W_var + (size_t)j * Hd;
    float pm = 0.f, pv = 0.f;
#pragma unroll
    for (int i = 0; i < 16; ++i) {
      float hv = hs[lane + 64 * i];
      pm = fmaf(Wm[lane + 64 * i], hv, pm);
      pv = fmaf(Wv[lane + 64 * i], hv, pv);
    }
#pragma unroll
    for (int off = 32; off; off >>= 1) {
      pm += __shfl_xor(pm, off, 64); pv += __shfl_xor(pv, off, 64);
    }
    if (lane == 0) {
      float m = pm + b_mean[j];
      float lv = pv + b_var[j];
      dout[2048064 + j] = m;
      dout[2048320 + j] = lv;
      float latv = m + eps[j] * __expf(0.5f * lv);
      st_flag(mbq + MB_H_PAIRS + j, latv);
    }
  }

  // ---- poll latent, build [latent | tense] in LDS ----
  if (tid < 128) {
    float4 a = poll16(mb + MB_H_PAIRS + 2 * tid);
    lat[2 * tid] = a.x; lat[2 * tid + 1] = a.z;
  } else if (tid < 160) {
    lat[256 + (tid - 128)] = ws[OFF_TEN + (tid - 128)];
  }
  __syncthreads();

  // ---- dec_h0[j] = W_l2h[j]·[latent|tense] + b ----
  {
    const float* Wr = W_l2h + (size_t)j * 288;
    float p = fmaf(Wr[lane], lat[lane], 0.f);
    p = fmaf(Wr[lane + 64], lat[lane + 64], p);
    p = fmaf(Wr[lane + 128], lat[lane + 128], p);
    p = fmaf(Wr[lane + 192], lat[lane + 192], p);
    if (lane < 32) p = fmaf(Wr[lane + 256], lat[lane + 256], p);
#pragma unroll
    for (int off = 32; off; off >>= 1) p += __shfl_xor(p, off, 64);
    if (lane == 0) st_flag(mbq + (size_t)65 * 1024 + j, p + b_l2h[j]);
  }
  __syncthreads();   // all lat reads done before decoder reuses hsbuf

  // ---- decoder ----
  c_reg = 0.f;
  gb0 = Gdec[j]; gb1 = Gdec[1024 + j]; gb2 = Gdec[2048 + j]; gb3 = Gdec[3072 + j];
  for (int t = 0; t < Td; ++t) {
    stage1024(mb + (size_t)(65 + t) * 1024, hsbuf[t & 1], tid);
    const float* hs = hsbuf[t & 1];
    float p0 = 0.f, p1 = 0.f, p2 = 0.f, p3 = 0.f;
#pragma unroll
    for (int i = 0; i < 16; ++i) {
      float hv = hs[lane + 64 * i];
      p0 = fmaf(wd[0][i], hv, p0);
      p1 = fmaf(wd[1][i], hv, p1);
      p2 = fmaf(wd[2][i], hv, p2);
      p3 = fmaf(wd[3][i], hv, p3);
    }
#pragma unroll
    for (int off = 32; off; off >>= 1) {
      p0 += __shfl_xor(p0, off, 64); p1 += __shfl_xor(p1, off, 64);
      p2 += __shfl_xor(p2, off, 64); p3 += __shfl_xor(p3, off, 64);
    }
    float gi = gb0 + p0, gf = gb1 + p1, gg = gb2 + p2, go = gb3 + p3;
    c_reg = fsigm(gf) * c_reg + fsigm(gi) * ftanh(gg);
    float hval = fsigm(go) * ftanh(c_reg);
    if (lane == 0) {
      if (t + 1 < Td) st_flag(mbq + (size_t)(66 + t) * 1024 + j, hval);
      h_all[(size_t)t * Hd + j] = hval;
    }
    if (t + 1 < Td) {
      gb0 = Gdec[(t + 1) * 4096 + j];
      gb1 = Gdec[(t + 1) * 4096 + 1024 + j];
      gb2 = Gdec[(t + 1) * 4096 + 2048 + j];
      gb3 = Gdec[(t + 1) * 4096 + 3072 + j];
    }
  }
}

// ---------------- log-softmax stats: per quarter-row {max, argmax, sumexp} --
__global__ __launch_bounds__(256) void lstats_kernel(const float* __restrict__ logits,
                                                     float* __restrict__ sd) {
  const int blk = blockIdx.x, t = blk >> 2, q = blk & 3, tid = threadIdx.x;
  const float* row = logits + (size_t)t * Vd + q * 8000;
  __shared__ float sm[256];
  __shared__ int si[256];
  float m = -INFINITY; int mi = 0x7fffffff;
  for (int v = tid; v < 8000; v += 256) {
    float x = row[v];
    if (x > m) { m = x; mi = v; }
  }
  sm[tid] = m; si[tid] = mi;
  __syncthreads();
  for (int s = 128; s > 0; s >>= 1) {
    if (tid < s) {
      float om = sm[tid + s]; int oi = si[tid + s];
      if (om > sm[tid] || (om == sm[tid] && oi < si[tid])) { sm[tid] = om; si[tid] = oi; }
    }
    __syncthreads();
  }
  float rm = sm[0]; int ri = si[0];
  __syncthreads();
  float s = 0.f;
  for (int v = tid; v < 8000; v += 256) s += __expf(row[v] - rm);
  sm[tid] = s;
  __syncthreads();
  for (int st = 128; st > 0; st >>= 1) {
    if (tid < st) sm[tid] += sm[tid + st];
    __syncthreads();
  }
  if (tid == 0) {
    sd[blk * 4 + 0] = rm;
    sd[blk * 4 + 1] = (float)(ri + q * 8000);
    sd[blk * 4 + 2] = sm[0];
  }
}

// ---------------- combine + normalize quarter-row ----------------------------
__global__ __launch_bounds__(256) void lfin_kernel(float* __restrict__ out,
                                                   const float* __restrict__ sd) {
  const int blk = blockIdx.x, t = blk >> 2, q = blk & 3, tid = threadIdx.x;
  float M = -INFINITY;
#pragma unroll
  for (int k = 0; k < 4; ++k) M = fmaxf(M, sd[t * 16 + k * 4]);
  float S = 0.f;
#pragma unroll
  for (int k = 0; k < 4; ++k) S += sd[t * 16 + k * 4 + 2] * __expf(sd[t * 16 + k * 4] - M);
  float corr = M + logf(S);
  float4* r4 = (float4*)(out + 64 + (size_t)t * Vd + q * 8000);
  for (int i = tid; i < 2000; i += 256) {
    float4 v = r4[i];
    v.x -= corr; v.y -= corr; v.z -= corr; v.w -= corr;
    r4[i] = v;
  }
  if (q == 0 && tid == 0) {
    float bm = -INFINITY; int bi = 0;
#pragma unroll
    for (int k = 0; k < 4; ++k) {
      float m = sd[t * 16 + k * 4];
      if (m > bm) { bm = m; bi = (int)sd[t * 16 + k * 4 + 1]; }
    }
    out[t] = (float)bi;
  }
}

extern "C" void kernel_launch(void* const* d_in, const int* in_sizes, int n_in,
                              void* d_out, int out_size, void* d_ws, size_t ws_size,
                              hipStream_t stream) {
  (void)in_sizes; (void)n_in; (void)out_size; (void)ws_size;
  const int* word       = (const int*)d_in[0];
  const int* tense      = (const int*)d_in[1];
  const float* tense_emb = (const float*)d_in[3];
  const float* enc_emb   = (const float*)d_in[4];
  const float* enc_Wih   = (const float*)d_in[5];
  const float* enc_Whh   = (const float*)d_in[6];
  const float* enc_bih   = (const float*)d_in[7];
  const float* enc_bhh   = (const float*)d_in[8];
  const float* W_mean    = (const float*)d_in[9];
  const float* b_mean    = (const float*)d_in[10];
  const float* W_var     = (const float*)d_in[11];
  const float* b_var     = (const float*)d_in[12];
  const float* W_l2h     = (const float*)d_in[13];
  const float* b_l2h     = (const float*)d_in[14];
  const float* dec_emb   = (const float*)d_in[15];
  const float* dec_Wih   = (const float*)d_in[16];
  const float* dec_Whh   = (const float*)d_in[17];
  const float* dec_bih   = (const float*)d_in[18];
  const float* dec_bhh   = (const float*)d_in[19];
  const float* W_out     = (const float*)d_in[20];
  const float* b_out     = (const float*)d_in[21];
  const float* eps       = (const float*)d_in[22];
  float* out = (float*)d_out;
  float* ws  = (float*)d_ws;

  prep_kernel<<<512, 256, 0, stream>>>(word, tense, tense_emb, enc_emb, dec_emb,
                                       enc_bih, enc_bhh, dec_bih, dec_bhh, ws);
  gemm_dual_kernel<<<128, 256, 0, stream>>>(enc_Wih, ws + OFF_ENCX, ws + OFF_BSE, ws + OFF_GENC,
                                            dec_Wih, ws + OFF_DECX, ws + OFF_BSD, ws + OFF_GDEC);
  seq_kernel<<<128, 512, 0, stream>>>(enc_Whh, dec_Whh, W_mean, b_mean, W_var, b_var,
                                      W_l2h, b_l2h, eps, ws, out);
  gemm_kernel<<<500, 256, 0, stream>>>(W_out, ws + OFF_HALL, b_out, out + 64, 32000);
  lstats_kernel<<<256, 256, 0, stream>>>(out + 64, ws + OFF_STATS);
  lfin_kernel<<<256, 256, 0, stream>>>(out, ws + OFF_STATS);
}